// Round 7
// baseline (492.817 us; speedup 1.0000x reference)
//
#include <hip/hip_runtime.h>
#include <math.h>

typedef _Float16 f16;
typedef _Float16 f16x2 __attribute__((ext_vector_type(2)));
typedef _Float16 f16x4 __attribute__((ext_vector_type(4)));
typedef _Float16 f16x8 __attribute__((ext_vector_type(8)));

#if defined(__has_builtin)
#if __has_builtin(__builtin_amdgcn_fdot2)
#define USE_FDOT2 1
#endif
#if __has_builtin(__builtin_amdgcn_exp2f)
#define USE_EXP2 1
#endif
#endif

__device__ __forceinline__ float fdot2f(f16x2 a, f16x2 b, float c) {
#ifdef USE_FDOT2
    return __builtin_amdgcn_fdot2(a, b, c, false);
#else
    return c + (float)a.x * (float)b.x + (float)a.y * (float)b.y;
#endif
}
__device__ __forceinline__ float exp2fast(float a) {
#ifdef USE_EXP2
    return __builtin_amdgcn_exp2f(a);
#else
    return exp2f(a);
#endif
}

namespace {
// 192 real kv rows (V=2 x 6 in-range t2 x NN=4 x DD=4); 320 zero rows folded analytically.
constexpr int NKV = 192, NVP = 96;
constexpr int KS  = 40;                 // f16 per k row (32 data + 8 pad), mult of 8 for f16x8
constexpr int VSP = 72;                 // f16 per v pair-row (64 data + 8 pad)
constexpr int QLS = 40;                 // f16 per q row in LDS
constexpr int KBYTES = NKV * KS * 2;    // 15360
constexpr int VBYTES = NVP * VSP * 2;   // 13824
constexpr int QBYTES = 128 * QLS * 2;   // 10240
constexpr float C1  = 0.2550600f;       // (1/sqrt(32)) * log2(e)
constexpr float CZN = -5.7707801f;      // -4*log2(e)  (fixed softmax shift, scores are tiny)
constexpr float CZV = 2.5511480f;       // CZN + log2(320): 320 identical zero-token kv rows
}

// LayerNorm one 64-ch token row into PACKED f16x2[32] (32 VGPRs). All indices static.
__device__ __forceinline__ void ln_row_f16(const float* __restrict__ xrow,
                                           const float* __restrict__ ls,
                                           const float* __restrict__ lb,
                                           f16x2 h2[32]) {
    float s = 0.f, ss = 0.f;
    #pragma unroll
    for (int i = 0; i < 16; ++i) {
        const float4 t = ((const float4*)xrow)[i];
        s  += (t.x + t.y) + (t.z + t.w);
        ss += t.x*t.x + t.y*t.y + t.z*t.z + t.w*t.w;
        h2[2*i]   = (f16x2){(f16)t.x, (f16)t.y};
        h2[2*i+1] = (f16x2){(f16)t.z, (f16)t.w};
    }
    const float mean = s * 0.015625f;
    const float rstd = rsqrtf(ss * 0.015625f - mean*mean + 1e-5f);
    #pragma unroll
    for (int i = 0; i < 32; ++i) {
        const float a0 = ((float)h2[i].x - mean) * rstd * ls[2*i]   + lb[2*i];
        const float a1 = ((float)h2[i].y - mean) * rstd * ls[2*i+1] + lb[2*i+1];
        h2[i] = (f16x2){(f16)a0, (f16)a1};
    }
}

// acc[0..NACC) += h2(64 ch packed) @ W (row stride `stride`), weights wave-uniform.
// MUST be fully unrolled: a runtime fp index sends h2[] to scratch (rule #20;
// r3-r5 regression: partial unroll -> 67MB scratch writes, 4x slowdown).
template<int NACC>
__device__ __forceinline__ void projh(const f16x2* __restrict__ h2,
                                      const float* __restrict__ wbase,
                                      const int stride, float* __restrict__ acc) {
    #pragma unroll
    for (int fp = 0; fp < 32; ++fp) {
        const float h0 = (float)h2[fp].x, h1 = (float)h2[fp].y;
        const float* w0 = wbase + (2*fp) * stride;
        const float* w1 = w0 + stride;
        #pragma unroll
        for (int j = 0; j < NACC; ++j)
            acc[j] = fmaf(h0, w0[j], fmaf(h1, w1[j], acc[j]));
    }
}

// ---------------- Kernel 1: per-(window,head) attention, o -> d_out (f16) ----------------
__global__ __launch_bounds__(256, 3) void k_att(
    const float* __restrict__ x,
    const float* __restrict__ ln1_s, const float* __restrict__ ln1_b,
    const float* __restrict__ Wq, const float* __restrict__ Wkv, const float* __restrict__ bkv,
    f16* __restrict__ o_out)
{
    __shared__ __align__(16) char smem[KBYTES + VBYTES + QBYTES];  // 39424 B
    f16* kl = (f16*)smem;                           // [192][KS]
    f16* vl = (f16*)(smem + KBYTES);                // [96 pairs][VSP]
    f16* ql = (f16*)(smem + KBYTES + VBYTES);       // [128][QLS]
    float* mrg = (float*)smem;                      // overlay [128][33] f32 after flash

    const int tid  = threadIdx.x;
    const int bid  = blockIdx.x;
    const int w    = bid & 511;            // window
    const int head = bid >> 9;
    const int cb   = head * 32;
    const int n    = w & 255;
    const int t    = w >> 8;

    // ---- staging: waves 0-2 (tid<192) project the 192 real kv rows;
    //      wave 3 (tid 192-255) projects the 128 q rows (2 rows/thread) into ql.
    if (tid < NKV) {
        const int r  = tid;
        const int v_ = (r >= 96) ? 1 : 0;
        const int rem = r - v_ * 96;
        const int t2i = rem >> 4, nn = (rem >> 2) & 3, dd = rem & 3;
        const int t2 = t2i + (t == 0 ? 2 : 0);     // in-range t2 values only
        int tsrc, tt;
        if (t2 < 2)      { tsrc = t - 1; tt = t2 + 2; }
        else if (t2 < 6) { tsrc = t;     tt = t2 - 2; }
        else             { tsrc = t + 1; tt = t2 - 6; }
        f16x2 h2[32];
        const size_t tok = ((size_t)(v_ * 8 + tsrc * 4 + tt) * 1024 + n * 4 + nn) * 4 + dd;
        ln_row_f16(x + tok * 64, ln1_s, ln1_b, h2);
        #pragma unroll 1
        for (int which = 0; which < 2; ++which) {
            const int cbase = 128 * which + cb;
            #pragma unroll 1
            for (int chunk = 0; chunk < 2; ++chunk) {
                float acc[16];
                #pragma unroll
                for (int j = 0; j < 16; ++j) acc[j] = bkv[cbase + chunk * 16 + j];
                projh<16>(h2, Wkv + cbase + chunk * 16, 256, acc);
                if (which == 0) {
                    f16x8 p0, p1;
                    #pragma unroll
                    for (int j = 0; j < 8; ++j) { p0[j] = (f16)acc[j]; p1[j] = (f16)acc[j + 8]; }
                    ((f16x8*)(kl + r * KS + chunk * 16))[0] = p0;
                    ((f16x8*)(kl + r * KS + chunk * 16 + 8))[0] = p1;
                } else {
                    // pair-interleave: vl[pair][2*c + (r&1)] = v[r][c]
                    #pragma unroll
                    for (int j = 0; j < 16; ++j)
                        vl[(r >> 1) * VSP + (chunk * 16 + j) * 2 + (r & 1)] = (f16)acc[j];
                }
            }
        }
    } else {
        const int u = tid - NKV;              // 0..63
        #pragma unroll 1
        for (int qq = 0; qq < 2; ++qq) {
            const int qr = u + qq * 64;       // q row 0..127
            const int v_ = qr >> 6, tt = (qr >> 4) & 3, nn = (qr >> 2) & 3, dd = qr & 3;
            const size_t tok = ((size_t)(v_ * 8 + t * 4 + tt) * 1024 + n * 4 + nn) * 4 + dd;
            f16x2 h2[32];
            ln_row_f16(x + tok * 64, ln1_s, ln1_b, h2);
            #pragma unroll 1
            for (int chunk = 0; chunk < 2; ++chunk) {
                float acc[16];
                #pragma unroll
                for (int j = 0; j < 16; ++j) acc[j] = 0.f;   // q has no bias
                projh<16>(h2, Wq + cb + chunk * 16, 128, acc);
                f16x8 p0, p1;
                #pragma unroll
                for (int j = 0; j < 8; ++j) { p0[j] = (f16)acc[j]; p1[j] = (f16)acc[j + 8]; }
                ((f16x8*)(ql + qr * QLS + chunk * 16))[0] = p0;
                ((f16x8*)(ql + qr * QLS + chunk * 16 + 8))[0] = p1;
            }
        }
    }
    __syncthreads();

    // ---- flash over 96 real kv rows per half (2-way kv split) + analytic zero-row
    const int r    = tid & 127;
    const int half = tid >> 7;
    const int v_   = r >> 6, tt = (r >> 4) & 3, nn = (r >> 2) & 3, dd = r & 3;
    const size_t qtok = ((size_t)(v_ * 8 + t * 4 + tt) * 1024 + n * 4 + nn) * 4 + dd;

    f16x2 q2[16];
    {
        const f16x8* qp = (const f16x8*)(ql + r * QLS);
        #pragma unroll
        for (int m = 0; m < 4; ++m) {
            const f16x8 qv = qp[m];
            #pragma unroll
            for (int i = 0; i < 4; ++i) q2[4*m + i] = (f16x2){qv[2*i], qv[2*i + 1]};
        }
    }

    float l = 0.f;
    float acc[32];
    #pragma unroll
    for (int j = 0; j < 32; ++j) acc[j] = 0.f;

    if (half == 0) {  // 320 zero tokens (depth halo + OOR time halo): k=bkv_k, v=bkv_v
        float sz = 0.f;
        #pragma unroll
        for (int j = 0; j < 16; ++j)
            sz += (float)q2[j].x * bkv[cb + 2*j] + (float)q2[j].y * bkv[cb + 2*j + 1];
        const float pz = exp2fast(fmaf(sz, C1, CZV));
        l = pz;
        #pragma unroll
        for (int j = 0; j < 32; ++j) acc[j] = pz * bkv[128 + cb + j];
    }

    const int pbase = half * (NVP / 2);
    #pragma unroll 2
    for (int p = pbase; p < pbase + (NVP / 2); ++p) {
        const f16x8* k0 = (const f16x8*)(kl + (2 * p) * KS);
        const f16x8* k1 = (const f16x8*)(kl + (2 * p + 1) * KS);
        float s0 = 0.f, s1 = 0.f;
        #pragma unroll
        for (int m = 0; m < 4; ++m) {
            const f16x8 a = k0[m], b = k1[m];
            s0 = fdot2f(q2[4*m+0], (f16x2){a[0], a[1]}, s0);
            s0 = fdot2f(q2[4*m+1], (f16x2){a[2], a[3]}, s0);
            s0 = fdot2f(q2[4*m+2], (f16x2){a[4], a[5]}, s0);
            s0 = fdot2f(q2[4*m+3], (f16x2){a[6], a[7]}, s0);
            s1 = fdot2f(q2[4*m+0], (f16x2){b[0], b[1]}, s1);
            s1 = fdot2f(q2[4*m+1], (f16x2){b[2], b[3]}, s1);
            s1 = fdot2f(q2[4*m+2], (f16x2){b[4], b[5]}, s1);
            s1 = fdot2f(q2[4*m+3], (f16x2){b[6], b[7]}, s1);
        }
        const float e0 = exp2fast(fmaf(s0, C1, CZN));
        const float e1 = exp2fast(fmaf(s1, C1, CZN));
        l += e0 + e1;
        const f16x2 pk = (f16x2){(f16)e0, (f16)e1};
        const f16x8* vv = (const f16x8*)(vl + p * VSP);
        #pragma unroll
        for (int m = 0; m < 8; ++m) {
            const f16x8 wv = vv[m];
            acc[4*m+0] = fdot2f(pk, (f16x2){wv[0], wv[1]}, acc[4*m+0]);
            acc[4*m+1] = fdot2f(pk, (f16x2){wv[2], wv[3]}, acc[4*m+1]);
            acc[4*m+2] = fdot2f(pk, (f16x2){wv[4], wv[5]}, acc[4*m+2]);
            acc[4*m+3] = fdot2f(pk, (f16x2){wv[6], wv[7]}, acc[4*m+3]);
        }
    }

    __syncthreads();            // flash reads of kl/vl/ql complete
    if (half) {
        float* mr = mrg + r * 33;
        #pragma unroll
        for (int j = 0; j < 32; ++j) mr[j] = acc[j];
        mr[32] = l;
    }
    __syncthreads();
    if (!half) {
        const float* mr = mrg + r * 33;
        const float inv = 1.0f / (l + mr[32]);
        f16* op = o_out + qtok * 128 + cb;
        #pragma unroll
        for (int m = 0; m < 8; ++m) {
            f16x4 st;
            st.x = (f16)((acc[4*m+0] + mr[4*m+0]) * inv);
            st.y = (f16)((acc[4*m+1] + mr[4*m+1]) * inv);
            st.z = (f16)((acc[4*m+2] + mr[4*m+2]) * inv);
            st.w = (f16)((acc[4*m+3] + mr[4*m+3]) * inv);
            ((f16x4*)op)[m] = st;
        }
    }
}

// ---------------- Kernel 2: row-local epilogue (upd, residual, LN2, MLP, residual) ----------
__global__ __launch_bounds__(256, 3) void k_epi(
    const float* __restrict__ x, const f16* __restrict__ o_in,
    const float* __restrict__ Wo, const float* __restrict__ bo, const float* __restrict__ gamma,
    const float* __restrict__ ln2_s, const float* __restrict__ ln2_b,
    const float* __restrict__ W1, const float* __restrict__ b1,
    const float* __restrict__ W2, const float* __restrict__ b2,
    const float* __restrict__ gm, float* __restrict__ out)
{
    constexpr int OLS = 132, H2S = 68, REDS = 9;
    __shared__ __align__(16) char smem[64 * OLS * 2 + 64 * H2S * 2 + 64 * REDS * 4]; // 27904 B
    f16* ol   = (f16*)smem;                         // [64][132]
    f16* h2l  = (f16*)(smem + 64 * OLS * 2);        // [64][68]
    float* red = (float*)(smem + 64 * OLS * 2 + 64 * H2S * 2); // [64][9]
    f16* hidl = ol;                                  // overlay (o dead after upd)

    const int tid = threadIdx.x;
    const int r = tid & 63, s = tid >> 6;
    const int f0 = s * 16;
    const size_t tok = (size_t)blockIdx.x * 64 + r;

    {   // stage o rows (coalesced within wave: fixed s, r = lane)
        const f16x4* src = (const f16x4*)(o_in + tok * 128 + s * 32);
        f16x4* dst = (f16x4*)(ol + r * OLS + s * 32);
        #pragma unroll
        for (int m = 0; m < 8; ++m) dst[m] = src[m];
    }
    __syncthreads();

    float upd[16];
    #pragma unroll
    for (int j = 0; j < 16; ++j) upd[j] = bo[f0 + j];
    {   // upd[f0..f0+16) = o_row @ Wo
        const f16x4* orow = (const f16x4*)(ol + r * OLS);
        #pragma unroll 8
        for (int m = 0; m < 32; ++m) {
            const f16x4 c4 = orow[m];
            const float c0 = (float)c4.x, c1 = (float)c4.y, c2 = (float)c4.z, c3 = (float)c4.w;
            const float* w0 = Wo + (4*m+0) * 64 + f0;
            const float* w1 = Wo + (4*m+1) * 64 + f0;
            const float* w2 = Wo + (4*m+2) * 64 + f0;
            const float* w3 = Wo + (4*m+3) * 64 + f0;
            #pragma unroll
            for (int j = 0; j < 16; ++j)
                upd[j] = fmaf(c0, w0[j], fmaf(c1, w1[j], fmaf(c2, w2[j], fmaf(c3, w3[j], upd[j]))));
        }
    }

    float tv[16]; float s1 = 0.f, s2 = 0.f;
    {   // residual; LN2 partial stats
        const float* xr = x + tok * 64 + f0;
        #pragma unroll
        for (int j = 0; j < 16; ++j) {
            const float tk = xr[j] + gamma[f0 + j] * upd[j];
            tv[j] = tk; s1 += tk; s2 += tk * tk;
        }
    }
    red[r * REDS + s * 2]     = s1;
    red[r * REDS + s * 2 + 1] = s2;
    __syncthreads();
    {   // LN2 finalize -> h2 (f16)
        const float a1 = red[r*REDS+0] + red[r*REDS+2] + red[r*REDS+4] + red[r*REDS+6];
        const float a2 = red[r*REDS+1] + red[r*REDS+3] + red[r*REDS+5] + red[r*REDS+7];
        const float mean = a1 * 0.015625f;
        const float var  = a2 * 0.015625f - mean * mean;
        const float rstd = rsqrtf(var + 1e-5f);
        #pragma unroll
        for (int j = 0; j < 16; ++j)
            h2l[r * H2S + f0 + j] = (f16)((tv[j] - mean) * rstd * ln2_s[f0 + j] + ln2_b[f0 + j]);
    }
    __syncthreads();
    {   // MLP1 + gelu(tanh) -> hid (f16, overlays o); hidden split 2x16 to bound live regs
        #pragma unroll 1
        for (int hb = 0; hb < 2; ++hb) {
            const int a0 = s * 32 + hb * 16;
            float ha[16];
            #pragma unroll
            for (int j = 0; j < 16; ++j) ha[j] = b1[a0 + j];
            const f16x4* h2row = (const f16x4*)(h2l + r * H2S);
            #pragma unroll 8
            for (int m = 0; m < 16; ++m) {
                const f16x4 c4 = h2row[m];
                const float c0 = (float)c4.x, c1 = (float)c4.y, c2 = (float)c4.z, c3 = (float)c4.w;
                const float* w0 = W1 + (4*m+0) * 128 + a0;
                const float* w1 = W1 + (4*m+1) * 128 + a0;
                const float* w2 = W1 + (4*m+2) * 128 + a0;
                const float* w3 = W1 + (4*m+3) * 128 + a0;
                #pragma unroll
                for (int j = 0; j < 16; ++j)
                    ha[j] = fmaf(c0, w0[j], fmaf(c1, w1[j], fmaf(c2, w2[j], fmaf(c3, w3[j], ha[j]))));
            }
            #pragma unroll
            for (int j = 0; j < 16; ++j) {
                const float z = ha[j];
                const float u = 0.7978845608028654f * (z + 0.044715f * z * z * z);
                hidl[r * OLS + a0 + j] = (f16)(0.5f * z * (1.0f + tanhf(u)));
            }
        }
    }
    __syncthreads();
    {   // MLP2 + final residual -> out (f32, same bytes o came from)
        float oa[16];
        #pragma unroll
        for (int j = 0; j < 16; ++j) oa[j] = b2[f0 + j];
        const f16x4* hrow = (const f16x4*)(hidl + r * OLS);
        #pragma unroll 8
        for (int m = 0; m < 32; ++m) {
            const f16x4 c4 = hrow[m];
            const float c0 = (float)c4.x, c1 = (float)c4.y, c2 = (float)c4.z, c3 = (float)c4.w;
            const float* w0 = W2 + (4*m+0) * 64 + f0;
            const float* w1 = W2 + (4*m+1) * 64 + f0;
            const float* w2 = W2 + (4*m+2) * 64 + f0;
            const float* w3 = W2 + (4*m+3) * 64 + f0;
            #pragma unroll
            for (int j = 0; j < 16; ++j)
                oa[j] = fmaf(c0, w0[j], fmaf(c1, w1[j], fmaf(c2, w2[j], fmaf(c3, w3[j], oa[j]))));
        }
        float* orow = out + tok * 64 + f0;
        #pragma unroll
        for (int j = 0; j < 16; ++j) orow[j] = tv[j] + gm[f0 + j] * oa[j];
    }
}

extern "C" void kernel_launch(void* const* d_in, const int* in_sizes, int n_in,
                              void* d_out, int out_size, void* d_ws, size_t ws_size,
                              hipStream_t stream) {
    const float* x        = (const float*)d_in[0];
    const float* ln1_s    = (const float*)d_in[1];
    const float* ln1_b    = (const float*)d_in[2];
    const float* Wq       = (const float*)d_in[3];
    const float* Wkv      = (const float*)d_in[4];
    const float* bkv      = (const float*)d_in[5];
    const float* Wo       = (const float*)d_in[6];
    const float* bo       = (const float*)d_in[7];
    const float* gamma    = (const float*)d_in[8];
    const float* ln2_s    = (const float*)d_in[9];
    const float* ln2_b    = (const float*)d_in[10];
    const float* W1       = (const float*)d_in[11];
    const float* b1       = (const float*)d_in[12];
    const float* W2       = (const float*)d_in[13];
    const float* b2       = (const float*)d_in[14];
    const float* gamma_mlp= (const float*)d_in[15];

    // o (f16[65536][128]) aliases d_out (f32[65536][64]) — same 16.78 MB; tokens are
    // partitioned across windows so K_att writes and K_epi read/overwrite race-free.
    f16* o_buf = (f16*)d_out;
    float* out = (float*)d_out;

    hipLaunchKernelGGL(k_att, dim3(2048), dim3(256), 0, stream,
                       x, ln1_s, ln1_b, Wq, Wkv, bkv, o_buf);
    hipLaunchKernelGGL(k_epi, dim3(1024), dim3(256), 0, stream,
                       x, o_buf, Wo, bo, gamma, ln2_s, ln2_b, W1, b1, W2, b2, gamma_mlp, out);
}

// Round 8
// 347.417 us; speedup vs baseline: 1.4185x; 1.4185x over previous
//
#include <hip/hip_runtime.h>
#include <math.h>

typedef _Float16 f16;
typedef _Float16 f16x2 __attribute__((ext_vector_type(2)));
typedef _Float16 f16x4 __attribute__((ext_vector_type(4)));
typedef _Float16 f16x8 __attribute__((ext_vector_type(8)));

#if defined(__has_builtin)
#if __has_builtin(__builtin_amdgcn_fdot2)
#define USE_FDOT2 1
#endif
#if __has_builtin(__builtin_amdgcn_exp2f)
#define USE_EXP2 1
#endif
#endif

__device__ __forceinline__ float fdot2f(f16x2 a, f16x2 b, float c) {
#ifdef USE_FDOT2
    return __builtin_amdgcn_fdot2(a, b, c, false);
#else
    return c + (float)a.x * (float)b.x + (float)a.y * (float)b.y;
#endif
}
__device__ __forceinline__ float exp2fast(float a) {
#ifdef USE_EXP2
    return __builtin_amdgcn_exp2f(a);
#else
    return exp2f(a);
#endif
}

namespace {
// 192 real kv rows (V=2 x 6 in-range t2 x NN=4 x DD=4); 320 zero rows folded analytically.
constexpr int NKV = 192, NVP = 96;
constexpr int KS  = 40;                 // f16 per k row (32 data + 8 pad)
constexpr int VSP = 72;                 // f16 per v pair-row (64 data + 8 pad)
constexpr int KBYTES = NKV * KS * 2;    // 15360
constexpr int VBYTES = NVP * VSP * 2;   // 13824
constexpr float C1  = 0.2550600f;       // (1/sqrt(32)) * log2(e)
constexpr float CZN = -5.7707801f;      // -4*log2(e)  (fixed softmax shift, scores are tiny)
constexpr float CZV = 2.5511480f;       // CZN + log2(320): 320 identical zero-token kv rows
}

// LayerNorm one 64-ch token row into PACKED f16x2[32] (32 VGPRs). All indices static.
__device__ __forceinline__ void ln_row_f16(const float* __restrict__ xrow,
                                           const float* __restrict__ ls,
                                           const float* __restrict__ lb,
                                           f16x2 h2[32]) {
    float s = 0.f, ss = 0.f;
    #pragma unroll
    for (int i = 0; i < 16; ++i) {
        const float4 t = ((const float4*)xrow)[i];
        s  += (t.x + t.y) + (t.z + t.w);
        ss += t.x*t.x + t.y*t.y + t.z*t.z + t.w*t.w;
        h2[2*i]   = (f16x2){(f16)t.x, (f16)t.y};
        h2[2*i+1] = (f16x2){(f16)t.z, (f16)t.w};
    }
    const float mean = s * 0.015625f;
    const float rstd = rsqrtf(ss * 0.015625f - mean*mean + 1e-5f);
    #pragma unroll
    for (int i = 0; i < 32; ++i) {
        const float a0 = ((float)h2[i].x - mean) * rstd * ls[2*i]   + lb[2*i];
        const float a1 = ((float)h2[i].y - mean) * rstd * ls[2*i+1] + lb[2*i+1];
        h2[i] = (f16x2){(f16)a0, (f16)a1};
    }
}

// acc[0..NACC) += h2(64 ch packed) @ W (row stride `stride`), weights wave-uniform.
// MUST be fully unrolled: a runtime fp index sends h2[] to scratch (rule #20;
// r3-r5 regression: partial unroll -> 67MB scratch writes, 4x slowdown).
template<int NACC>
__device__ __forceinline__ void projh(const f16x2* __restrict__ h2,
                                      const float* __restrict__ wbase,
                                      const int stride, float* __restrict__ acc) {
    #pragma unroll
    for (int fp = 0; fp < 32; ++fp) {
        const float h0 = (float)h2[fp].x, h1 = (float)h2[fp].y;
        const float* w0 = wbase + (2*fp) * stride;
        const float* w1 = w0 + stride;
        #pragma unroll
        for (int j = 0; j < NACC; ++j)
            acc[j] = fmaf(h0, w0[j], fmaf(h1, w1[j], acc[j]));
    }
}

// ---------------- Kernel 1: per-(window,head) attention, o -> d_out (f16) ----------------
// Structure = round-6 known-good (q recomputed per flash thread; no q-LDS path,
// which re-triggered the scratch anomaly in r7) + 192-real-row staging and
// 320x analytic zero-row (work elimination).
__global__ __launch_bounds__(256, 3) void k_att(
    const float* __restrict__ x,
    const float* __restrict__ ln1_s, const float* __restrict__ ln1_b,
    const float* __restrict__ Wq, const float* __restrict__ Wkv, const float* __restrict__ bkv,
    f16* __restrict__ o_out)
{
    __shared__ __align__(16) char smem[KBYTES + VBYTES];   // 29184 B
    f16* kl = (f16*)smem;                  // [192][KS]
    f16* vl = (f16*)(smem + KBYTES);       // [96 pairs][VSP]
    float* mrg = (float*)smem;             // overlay [128][33] f32 after flash (16896 B)

    const int tid  = threadIdx.x;
    const int bid  = blockIdx.x;
    const int w    = bid & 511;            // window
    const int head = bid >> 9;
    const int cb   = head * 32;
    const int n    = w & 255;
    const int t    = w >> 8;

    // ---- staging: threads 0-191 project the 192 real kv rows; wave 3 idles.
    if (tid < NKV) {
        const int r  = tid;
        const int v_ = (r >= 96) ? 1 : 0;
        const int rem = r - v_ * 96;
        const int t2i = rem >> 4, nn = (rem >> 2) & 3, dd = rem & 3;
        const int t2 = t2i + (t == 0 ? 2 : 0);     // in-range t2 values only
        int tsrc, tt;
        if (t2 < 2)      { tsrc = t - 1; tt = t2 + 2; }
        else if (t2 < 6) { tsrc = t;     tt = t2 - 2; }
        else             { tsrc = t + 1; tt = t2 - 6; }
        f16x2 h2[32];
        const size_t tok = ((size_t)(v_ * 8 + tsrc * 4 + tt) * 1024 + n * 4 + nn) * 4 + dd;
        ln_row_f16(x + tok * 64, ln1_s, ln1_b, h2);
        #pragma unroll 1
        for (int which = 0; which < 2; ++which) {
            const int cbase = 128 * which + cb;
            #pragma unroll 1
            for (int chunk = 0; chunk < 2; ++chunk) {
                float acc[16];
                #pragma unroll
                for (int j = 0; j < 16; ++j) acc[j] = bkv[cbase + chunk * 16 + j];
                projh<16>(h2, Wkv + cbase + chunk * 16, 256, acc);
                if (which == 0) {
                    f16x8 p0, p1;
                    #pragma unroll
                    for (int j = 0; j < 8; ++j) { p0[j] = (f16)acc[j]; p1[j] = (f16)acc[j + 8]; }
                    ((f16x8*)(kl + r * KS + chunk * 16))[0] = p0;
                    ((f16x8*)(kl + r * KS + chunk * 16 + 8))[0] = p1;
                } else {
                    // pair-interleave: vl[pair][2*c + (r&1)] = v[r][c]
                    #pragma unroll
                    for (int j = 0; j < 16; ++j)
                        vl[(r >> 1) * VSP + (chunk * 16 + j) * 2 + (r & 1)] = (f16)acc[j];
                }
            }
        }
    }
    __syncthreads();

    // ---- q projection (each half recomputes its row) + flash over 48 kv pairs/half
    const int r    = tid & 127;
    const int half = tid >> 7;
    const int v_   = r >> 6, tt = (r >> 4) & 3, nn = (r >> 2) & 3, dd = r & 3;
    const size_t qtok = ((size_t)(v_ * 8 + t * 4 + tt) * 1024 + n * 4 + nn) * 4 + dd;

    float l = 0.f;
    float acc[32];
    #pragma unroll
    for (int j = 0; j < 32; ++j) acc[j] = 0.f;
    f16x2 q2[16];
    {
        f16x2 h2[32];
        ln_row_f16(x + qtok * 64, ln1_s, ln1_b, h2);
        float qf[32];
        #pragma unroll
        for (int j = 0; j < 32; ++j) qf[j] = 0.f;
        projh<16>(h2, Wq + cb, 128, qf);
        projh<16>(h2, Wq + cb + 16, 128, qf + 16);

        if (half == 0) {  // 320 zero tokens (depth halo + OOR time halo): k=bkv_k, v=bkv_v
            float sz = 0.f;
            #pragma unroll
            for (int j = 0; j < 32; ++j) sz = fmaf(qf[j], bkv[cb + j], sz);
            const float pz = exp2fast(fmaf(sz, C1, CZV));
            l = pz;
            #pragma unroll
            for (int j = 0; j < 32; ++j) acc[j] = pz * bkv[128 + cb + j];
        }
        #pragma unroll
        for (int j = 0; j < 16; ++j) q2[j] = (f16x2){(f16)qf[2*j], (f16)qf[2*j+1]};
    }

    const int pbase = half * (NVP / 2);
    #pragma unroll 2
    for (int p = pbase; p < pbase + (NVP / 2); ++p) {
        const f16x8* k0 = (const f16x8*)(kl + (2 * p) * KS);
        const f16x8* k1 = (const f16x8*)(kl + (2 * p + 1) * KS);
        float s0 = 0.f, s1 = 0.f;
        #pragma unroll
        for (int m = 0; m < 4; ++m) {
            const f16x8 a = k0[m], b = k1[m];
            s0 = fdot2f(q2[4*m+0], (f16x2){a[0], a[1]}, s0);
            s0 = fdot2f(q2[4*m+1], (f16x2){a[2], a[3]}, s0);
            s0 = fdot2f(q2[4*m+2], (f16x2){a[4], a[5]}, s0);
            s0 = fdot2f(q2[4*m+3], (f16x2){a[6], a[7]}, s0);
            s1 = fdot2f(q2[4*m+0], (f16x2){b[0], b[1]}, s1);
            s1 = fdot2f(q2[4*m+1], (f16x2){b[2], b[3]}, s1);
            s1 = fdot2f(q2[4*m+2], (f16x2){b[4], b[5]}, s1);
            s1 = fdot2f(q2[4*m+3], (f16x2){b[6], b[7]}, s1);
        }
        const float e0 = exp2fast(fmaf(s0, C1, CZN));
        const float e1 = exp2fast(fmaf(s1, C1, CZN));
        l += e0 + e1;
        const f16x2 pk = (f16x2){(f16)e0, (f16)e1};
        const f16x8* vv = (const f16x8*)(vl + p * VSP);
        #pragma unroll
        for (int m = 0; m < 8; ++m) {
            const f16x8 wv = vv[m];
            acc[4*m+0] = fdot2f(pk, (f16x2){wv[0], wv[1]}, acc[4*m+0]);
            acc[4*m+1] = fdot2f(pk, (f16x2){wv[2], wv[3]}, acc[4*m+1]);
            acc[4*m+2] = fdot2f(pk, (f16x2){wv[4], wv[5]}, acc[4*m+2]);
            acc[4*m+3] = fdot2f(pk, (f16x2){wv[6], wv[7]}, acc[4*m+3]);
        }
    }

    __syncthreads();            // flash reads of kl/vl complete
    if (half) {
        float* mr = mrg + r * 33;
        #pragma unroll
        for (int j = 0; j < 32; ++j) mr[j] = acc[j];
        mr[32] = l;
    }
    __syncthreads();
    if (!half) {
        const float* mr = mrg + r * 33;
        const float inv = 1.0f / (l + mr[32]);
        f16* op = o_out + qtok * 128 + cb;
        #pragma unroll
        for (int m = 0; m < 8; ++m) {
            f16x4 st;
            st.x = (f16)((acc[4*m+0] + mr[4*m+0]) * inv);
            st.y = (f16)((acc[4*m+1] + mr[4*m+1]) * inv);
            st.z = (f16)((acc[4*m+2] + mr[4*m+2]) * inv);
            st.w = (f16)((acc[4*m+3] + mr[4*m+3]) * inv);
            ((f16x4*)op)[m] = st;
        }
    }
}

// ---------------- Kernel 2: row-local epilogue (upd, residual, LN2, MLP, residual) ----------
__global__ __launch_bounds__(256, 3) void k_epi(
    const float* __restrict__ x, const f16* __restrict__ o_in,
    const float* __restrict__ Wo, const float* __restrict__ bo, const float* __restrict__ gamma,
    const float* __restrict__ ln2_s, const float* __restrict__ ln2_b,
    const float* __restrict__ W1, const float* __restrict__ b1,
    const float* __restrict__ W2, const float* __restrict__ b2,
    const float* __restrict__ gm, float* __restrict__ out)
{
    constexpr int OLS = 132, H2S = 68, REDS = 9;
    __shared__ __align__(16) char smem[64 * OLS * 2 + 64 * H2S * 2 + 64 * REDS * 4]; // 27904 B
    f16* ol   = (f16*)smem;                         // [64][132]
    f16* h2l  = (f16*)(smem + 64 * OLS * 2);        // [64][68]
    float* red = (float*)(smem + 64 * OLS * 2 + 64 * H2S * 2); // [64][9]
    f16* hidl = ol;                                  // overlay (o dead after upd)

    const int tid = threadIdx.x;
    const int r = tid & 63, s = tid >> 6;
    const int f0 = s * 16;
    const size_t tok = (size_t)blockIdx.x * 64 + r;

    {   // stage o rows (coalesced within wave: fixed s, r = lane)
        const f16x4* src = (const f16x4*)(o_in + tok * 128 + s * 32);
        f16x4* dst = (f16x4*)(ol + r * OLS + s * 32);
        #pragma unroll
        for (int m = 0; m < 8; ++m) dst[m] = src[m];
    }
    __syncthreads();

    float upd[16];
    #pragma unroll
    for (int j = 0; j < 16; ++j) upd[j] = bo[f0 + j];
    {   // upd[f0..f0+16) = o_row @ Wo
        const f16x4* orow = (const f16x4*)(ol + r * OLS);
        #pragma unroll 8
        for (int m = 0; m < 32; ++m) {
            const f16x4 c4 = orow[m];
            const float c0 = (float)c4.x, c1 = (float)c4.y, c2 = (float)c4.z, c3 = (float)c4.w;
            const float* w0 = Wo + (4*m+0) * 64 + f0;
            const float* w1 = Wo + (4*m+1) * 64 + f0;
            const float* w2 = Wo + (4*m+2) * 64 + f0;
            const float* w3 = Wo + (4*m+3) * 64 + f0;
            #pragma unroll
            for (int j = 0; j < 16; ++j)
                upd[j] = fmaf(c0, w0[j], fmaf(c1, w1[j], fmaf(c2, w2[j], fmaf(c3, w3[j], upd[j]))));
        }
    }

    float tv[16]; float s1 = 0.f, s2 = 0.f;
    {   // residual; LN2 partial stats
        const float* xr = x + tok * 64 + f0;
        #pragma unroll
        for (int j = 0; j < 16; ++j) {
            const float tk = xr[j] + gamma[f0 + j] * upd[j];
            tv[j] = tk; s1 += tk; s2 += tk * tk;
        }
    }
    red[r * REDS + s * 2]     = s1;
    red[r * REDS + s * 2 + 1] = s2;
    __syncthreads();
    {   // LN2 finalize -> h2 (f16)
        const float a1 = red[r*REDS+0] + red[r*REDS+2] + red[r*REDS+4] + red[r*REDS+6];
        const float a2 = red[r*REDS+1] + red[r*REDS+3] + red[r*REDS+5] + red[r*REDS+7];
        const float mean = a1 * 0.015625f;
        const float var  = a2 * 0.015625f - mean * mean;
        const float rstd = rsqrtf(var + 1e-5f);
        #pragma unroll
        for (int j = 0; j < 16; ++j)
            h2l[r * H2S + f0 + j] = (f16)((tv[j] - mean) * rstd * ln2_s[f0 + j] + ln2_b[f0 + j]);
    }
    __syncthreads();
    {   // MLP1 + gelu(tanh) -> hid (f16, overlays o); hidden split 2x16 to bound live regs
        #pragma unroll 1
        for (int hb = 0; hb < 2; ++hb) {
            const int a0 = s * 32 + hb * 16;
            float ha[16];
            #pragma unroll
            for (int j = 0; j < 16; ++j) ha[j] = b1[a0 + j];
            const f16x4* h2row = (const f16x4*)(h2l + r * H2S);
            #pragma unroll 8
            for (int m = 0; m < 16; ++m) {
                const f16x4 c4 = h2row[m];
                const float c0 = (float)c4.x, c1 = (float)c4.y, c2 = (float)c4.z, c3 = (float)c4.w;
                const float* w0 = W1 + (4*m+0) * 128 + a0;
                const float* w1 = W1 + (4*m+1) * 128 + a0;
                const float* w2 = W1 + (4*m+2) * 128 + a0;
                const float* w3 = W1 + (4*m+3) * 128 + a0;
                #pragma unroll
                for (int j = 0; j < 16; ++j)
                    ha[j] = fmaf(c0, w0[j], fmaf(c1, w1[j], fmaf(c2, w2[j], fmaf(c3, w3[j], ha[j]))));
            }
            #pragma unroll
            for (int j = 0; j < 16; ++j) {
                const float z = ha[j];
                const float u = 0.7978845608028654f * (z + 0.044715f * z * z * z);
                hidl[r * OLS + a0 + j] = (f16)(0.5f * z * (1.0f + tanhf(u)));
            }
        }
    }
    __syncthreads();
    {   // MLP2 + final residual -> out (f32, same bytes o came from)
        float oa[16];
        #pragma unroll
        for (int j = 0; j < 16; ++j) oa[j] = b2[f0 + j];
        const f16x4* hrow = (const f16x4*)(hidl + r * OLS);
        #pragma unroll 8
        for (int m = 0; m < 32; ++m) {
            const f16x4 c4 = hrow[m];
            const float c0 = (float)c4.x, c1 = (float)c4.y, c2 = (float)c4.z, c3 = (float)c4.w;
            const float* w0 = W2 + (4*m+0) * 64 + f0;
            const float* w1 = W2 + (4*m+1) * 64 + f0;
            const float* w2 = W2 + (4*m+2) * 64 + f0;
            const float* w3 = W2 + (4*m+3) * 64 + f0;
            #pragma unroll
            for (int j = 0; j < 16; ++j)
                oa[j] = fmaf(c0, w0[j], fmaf(c1, w1[j], fmaf(c2, w2[j], fmaf(c3, w3[j], oa[j]))));
        }
        float* orow = out + tok * 64 + f0;
        #pragma unroll
        for (int j = 0; j < 16; ++j) orow[j] = tv[j] + gm[f0 + j] * oa[j];
    }
}

extern "C" void kernel_launch(void* const* d_in, const int* in_sizes, int n_in,
                              void* d_out, int out_size, void* d_ws, size_t ws_size,
                              hipStream_t stream) {
    const float* x        = (const float*)d_in[0];
    const float* ln1_s    = (const float*)d_in[1];
    const float* ln1_b    = (const float*)d_in[2];
    const float* Wq       = (const float*)d_in[3];
    const float* Wkv      = (const float*)d_in[4];
    const float* bkv      = (const float*)d_in[5];
    const float* Wo       = (const float*)d_in[6];
    const float* bo       = (const float*)d_in[7];
    const float* gamma    = (const float*)d_in[8];
    const float* ln2_s    = (const float*)d_in[9];
    const float* ln2_b    = (const float*)d_in[10];
    const float* W1       = (const float*)d_in[11];
    const float* b1       = (const float*)d_in[12];
    const float* W2       = (const float*)d_in[13];
    const float* b2       = (const float*)d_in[14];
    const float* gamma_mlp= (const float*)d_in[15];

    // o (f16[65536][128]) aliases d_out (f32[65536][64]) — same 16.78 MB; tokens are
    // partitioned across windows so K_att writes and K_epi read/overwrite race-free.
    f16* o_buf = (f16*)d_out;
    float* out = (float*)d_out;

    hipLaunchKernelGGL(k_att, dim3(2048), dim3(256), 0, stream,
                       x, ln1_s, ln1_b, Wq, Wkv, bkv, o_buf);
    hipLaunchKernelGGL(k_epi, dim3(1024), dim3(256), 0, stream,
                       x, o_buf, Wo, bo, gamma, ln2_s, ln2_b, W1, b1, W2, b2, gamma_mlp, out);
}